// Round 9
// baseline (436.646 us; speedup 1.0000x reference)
//
#include <hip/hip_runtime.h>

// Problem constants
constexpr int NB = 4, NS = 1024, NE = 1024, NH = 16, NFF = 4096;
constexpr int NM = NB * NS; // 4096 token rows

typedef short s8v __attribute__((ext_vector_type(8)));
typedef short s4v __attribute__((ext_vector_type(4)));
typedef float f4  __attribute__((ext_vector_type(4)));

__device__ __forceinline__ float b2f(unsigned short u) {
    union { unsigned int i; float f; } v; v.i = ((unsigned int)u) << 16; return v.f;
}
__device__ __forceinline__ unsigned short f2b(float f) {
    union { float f; unsigned int i; } v; v.f = f;
    unsigned int r = v.i + 0x7FFFu + ((v.i >> 16) & 1u);
    return (unsigned short)(r >> 16);
}
__device__ __forceinline__ float sigf(float x) { return 1.f / (1.f + __expf(-x)); }

#define GL2LDS(g, l) __builtin_amdgcn_global_load_lds( \
    (const __attribute__((address_space(1))) void*)(g), \
    (__attribute__((address_space(3))) void*)(l), 16, 0, 0)

// ---------------------------------------------------------------------------
// Fused prep: cvt_x + 5x(ExE transpose) + 2x(ExFF transpose) + 1x(FFxE
// transpose) + posmean, one launch.
__device__ __forceinline__ void cvt_t_tile(
    const float* __restrict__ W, unsigned short* __restrict__ WT,
    int K, int N, int bx, int by, int t, unsigned short L[64][72])
{
    const int k0 = by * 64, n0 = bx * 64;
    const int r = t >> 4, c4 = (t & 15) * 4;
#pragma unroll
    for (int p = 0; p < 4; p++) {
        int k = r + p * 16;
        f4 v = *(const f4*)&W[(size_t)(k0 + k) * N + n0 + c4];
#pragma unroll
        for (int i = 0; i < 4; i++) L[c4 + i][k] = f2b(v[i]);
    }
    __syncthreads();
    const int n = t >> 2, kc = (t & 3) * 16;
    s8v o0, o1;
#pragma unroll
    for (int i = 0; i < 8; i++) { o0[i] = (short)L[n][kc + i]; o1[i] = (short)L[n][kc + 8 + i]; }
    unsigned short* dst = WT + (size_t)(n0 + n) * K + k0 + kc;
    *(s8v*)dst = o0; *(s8v*)(dst + 8) = o1;
}

__global__ __launch_bounds__(256) void prep_kernel(
    const float* __restrict__ x, unsigned short* __restrict__ xb,
    const float* Wq, const float* Wk, const float* Wv, const float* Wg,
    const float* Wo,
    unsigned short* WTq, unsigned short* WoT,
    const float* Wf1, const float* Wfg, const float* Wf2,
    unsigned short* Wf1T, unsigned short* WfgT, unsigned short* Wf2T,
    const float* __restrict__ pe, float* __restrict__ biasP)
{
    __shared__ unsigned short L[64][72];
    const int t = threadIdx.x;
    int bid = blockIdx.x;

    if (bid < 2048) {  // ---- cvt_x: fp32 -> bf16, 4096x1024
        size_t i = ((size_t)bid * 256 + t) * 8;
        f4 v0 = *(const f4*)(x + i), v1 = *(const f4*)(x + i + 4);
        s8v o;
#pragma unroll
        for (int j = 0; j < 4; j++) { o[j] = (short)f2b(v0[j]); o[4 + j] = (short)f2b(v1[j]); }
        *(s8v*)(xb + i) = o;
        return;
    }
    bid -= 2048;
    if (bid < 1280) {  // ---- 5x ExE transpose
        int z = bid >> 8, rem = bid & 255;
        const float* W = (z == 0) ? Wq : (z == 1) ? Wk : (z == 2) ? Wv : (z == 3) ? Wg : Wo;
        unsigned short* WT = (z == 4) ? WoT : WTq + (size_t)z * 1024 * 1024;
        cvt_t_tile(W, WT, 1024, 1024, rem & 15, rem >> 4, t, L);
        return;
    }
    bid -= 1280;
    if (bid < 2048) {  // ---- Wf1 / Wfg transpose (K=1024, N=4096)
        int z = bid >> 10, rem = bid & 1023;
        cvt_t_tile(z ? Wfg : Wf1, z ? WfgT : Wf1T, 1024, 4096, rem & 63, rem >> 6, t, L);
        return;
    }
    bid -= 2048;
    if (bid < 1024) {  // ---- Wf2 transpose (K=4096, N=1024)
        cvt_t_tile(Wf2, Wf2T, 4096, 1024, bid & 15, bid >> 4, t, L);
        return;
    }
    bid -= 1024;
    {  // ---- posmean
        int idx = bid * 256 + t;
        const float* p = pe + (size_t)idx * 8;
        f4 v0 = *(const f4*)p, v1 = *(const f4*)(p + 4);
        float s = 0.f;
#pragma unroll
        for (int i = 0; i < 4; i++) s += v0[i] + v1[i];
        biasP[idx] = (s * 0.125f - 8.0f) * 1.44269504f;
    }
}

// ---------------------------------------------------------------------------
// MFMA GEMM, BT layout, 2-phase. Kept only for GATE_RES.
// OCCUPANCY RULE (R4): grid must stay >= 512 blocks.
template <int TM>
__global__ __launch_bounds__(256) void gemm_gate(
    const unsigned short* __restrict__ A,
    const unsigned short* __restrict__ BT,
    const float* b0p,
    const unsigned short* ex1, const unsigned short* ex2,
    unsigned short* C, int M, int N, int K)
{
    constexpr int AR = 32 * TM;
    __shared__ short As0[AR * 32], As1[AR * 32];
    __shared__ short Bs0[128 * 32], Bs1[128 * 32];

    const int tid  = threadIdx.x;
    const int m0   = blockIdx.y * AR;
    const int n0   = blockIdx.x * 128;
    const int lane = tid & 63;
    const int wave = tid >> 6;
    const int wm   = (wave >> 1) * (16 * TM), wn = (wave & 1) * 64;
    const int quad = lane >> 4, lo = lane & 15;
    const int lrow = lane >> 2;
    const int lcol = (((lane & 3) ^ ((lane >> 4) & 3))) * 8;
    const int rcol = ((quad ^ ((lo >> 2) & 3))) * 8;

    f4 acc[TM][4];
#pragma unroll
    for (int i = 0; i < TM; i++)
#pragma unroll
        for (int j = 0; j < 4; j++)
#pragma unroll
            for (int r = 0; r < 4; r++) acc[i][j][r] = 0.f;

    const unsigned short* ga = A  + (size_t)(m0 + wave * (AR / 4) + lrow) * K + lcol;
    const unsigned short* gb = BT + (size_t)(n0 + wave * 32 + lrow) * K + lcol;
    short* lA0  = &As0[(wave * (AR / 4)) * 32];
    short* lA1  = &As1[(wave * (AR / 4)) * 32];
    short* lB00 = &Bs0[(wave * 32) * 32];
    short* lB01 = &Bs0[(wave * 32 + 16) * 32];
    short* lB10 = &Bs1[(wave * 32) * 32];
    short* lB11 = &Bs1[(wave * 32 + 16) * 32];

    for (int k0 = 0; k0 < K; k0 += 64) {
#pragma unroll
        for (int t = 0; t < TM / 2; t++) {
            GL2LDS(ga + k0 +      (size_t)t * 16 * K, lA0 + t * 16 * 32);
            GL2LDS(ga + k0 + 32 + (size_t)t * 16 * K, lA1 + t * 16 * 32);
        }
        GL2LDS(gb + k0,               lB00);
        GL2LDS(gb + k0 + 16 * K,      lB01);
        GL2LDS(gb + k0 + 32,          lB10);
        GL2LDS(gb + k0 + 32 + 16 * K, lB11);
        __syncthreads();

        s8v af[TM], bf[4];
#pragma unroll
        for (int i = 0; i < TM; i++)
            af[i] = *(const s8v*)&As0[(wm + i * 16 + lo) * 32 + rcol];
#pragma unroll
        for (int j = 0; j < 4; j++)
            bf[j] = *(const s8v*)&Bs0[(wn + j * 16 + lo) * 32 + rcol];
#pragma unroll
        for (int i = 0; i < TM; i++)
#pragma unroll
            for (int j = 0; j < 4; j++)
                acc[i][j] = __builtin_amdgcn_mfma_f32_16x16x32_bf16(af[i], bf[j], acc[i][j], 0, 0, 0);
#pragma unroll
        for (int i = 0; i < TM; i++)
            af[i] = *(const s8v*)&As1[(wm + i * 16 + lo) * 32 + rcol];
#pragma unroll
        for (int j = 0; j < 4; j++)
            bf[j] = *(const s8v*)&Bs1[(wn + j * 16 + lo) * 32 + rcol];
#pragma unroll
        for (int i = 0; i < TM; i++)
#pragma unroll
            for (int j = 0; j < 4; j++)
                acc[i][j] = __builtin_amdgcn_mfma_f32_16x16x32_bf16(af[i], bf[j], acc[i][j], 0, 0, 0);
        __syncthreads();
    }

#pragma unroll
    for (int i = 0; i < TM; i++) {
#pragma unroll
        for (int j = 0; j < 4; j++) {
#pragma unroll
            for (int r = 0; r < 4; r++) {
                int gm = m0 + wm + i * 16 + quad * 4 + r;
                int gn = n0 + wn + j * 16 + lo;
                size_t idx = (size_t)gm * N + gn;
                float v = acc[i][j][r] + b0p[gn];
                v = b2f(ex1[idx]) + b2f(ex2[(size_t)gm * 4096 + gn]) * v;
                C[idx] = f2b(v);
            }
        }
    }
}

// ---------------------------------------------------------------------------
// 8-phase fused FF GEMM — DEDICATED kernel, R6/R8-verified (75.3-76.7 us,
// MfmaUtil 37%, conflicts 0, ~913 TF dual). DO NOT merge into a template
// (R7: co-compiled variant stretched it to 97.4 us).
__global__ __launch_bounds__(512, 1) void gemm_ff8(
    const unsigned short* __restrict__ A,
    const unsigned short* __restrict__ B1T,
    const unsigned short* __restrict__ B2T,
    const float* __restrict__ bias1, const float* __restrict__ bias2,
    unsigned short* __restrict__ C)
{
    __shared__ short Lds[8 * 8192];  // 128 KB

    const int tid  = threadIdx.x;
    const int ln   = tid & 63, wv = tid >> 6;
    const int wr   = wv >> 1, wc = wv & 1;      // wave grid 4M x 2N
    const int quad = ln >> 4, lo = ln & 15;
    const int m0   = blockIdx.y * 256, n0 = blockIdx.x * 128;

    const int rowst = wv * 8 + (ln >> 3);
    const int cosrc = ((ln & 7) ^ (ln >> 3)) * 8;
    short* const ldst0 = &Lds[(wv * 8) * 64];

    f4 accA[4][4], accB[4][4];
#pragma unroll
    for (int i = 0; i < 4; i++)
#pragma unroll
        for (int j = 0; j < 4; j++)
#pragma unroll
            for (int r = 0; r < 4; r++) { accA[i][j][r] = 0.f; accB[i][j][r] = 0.f; }

    auto stage_half = [&](int h) {
        if (h >= 64) return;
        const int tt = h >> 2, kind = h & 3, slot = h & 7;
        const unsigned short* gsrc;
        if (kind == 0)      gsrc = A   + (size_t)(m0 + rowst) * 1024 + tt * 64 + cosrc;
        else if (kind == 1) gsrc = A   + (size_t)(m0 + 128 + rowst) * 1024 + tt * 64 + cosrc;
        else if (kind == 2) gsrc = B1T + (size_t)(n0 + rowst) * 1024 + tt * 64 + cosrc;
        else                gsrc = B2T + (size_t)(n0 + rowst) * 1024 + tt * 64 + cosrc;
        short* ldst = ldst0 + slot * 8192;
        GL2LDS(gsrc,                     ldst);
        GL2LDS(gsrc + (size_t)64 * 1024, ldst + 64 * 64);
    };

    int aoff[2], boff[2];
#pragma unroll
    for (int kh = 0; kh < 2; kh++) {
        const int sw = (((kh * 4 + quad) ^ (lo & 7)) * 8);
        aoff[kh] = (((wr & 1) * 64 + lo) * 64) + sw;
        boff[kh] = ((wc * 64 + lo) * 64) + sw;
    }
    const int slA = wr >> 1;  // which A half this wave reads

    // prologue: halves 0..4 in flight; complete 0..3 (tile 0), allow half 4.
#pragma unroll
    for (int h = 0; h < 5; h++) stage_half(h);
    asm volatile("s_waitcnt vmcnt(2)" ::: "memory");
    __builtin_amdgcn_s_barrier();

    for (int t = 0; t < 16; t++) {
        const int p4 = (t & 1) * 4;
        const short* LA  = &Lds[(p4 + slA) * 8192];
        const short* LB1 = &Lds[(p4 + 2) * 8192];
        const short* LB2 = &Lds[(p4 + 3) * 8192];
        const int hb = 4 * t;
        s8v af[4], bf[4];

        // ---- P1: GEMM1 (Wf1), K-half 0
#pragma unroll
        for (int i = 0; i < 4; i++) af[i] = *(const s8v*)&LA[aoff[0] + i * 1024];
#pragma unroll
        for (int j = 0; j < 4; j++) bf[j] = *(const s8v*)&LB1[boff[0] + j * 1024];
        stage_half(hb + 5);
        __builtin_amdgcn_s_barrier();
        __builtin_amdgcn_s_setprio(1);
#pragma unroll
        for (int i = 0; i < 4; i++)
#pragma unroll
            for (int j = 0; j < 4; j++)
                accA[i][j] = __builtin_amdgcn_mfma_f32_16x16x32_bf16(af[i], bf[j], accA[i][j], 0, 0, 0);
        __builtin_amdgcn_s_setprio(0);
        __builtin_amdgcn_s_barrier();

        // ---- P2: GEMM2 (Wfg), K-half 0 (reuse af)
#pragma unroll
        for (int j = 0; j < 4; j++) bf[j] = *(const s8v*)&LB2[boff[0] + j * 1024];
        stage_half(hb + 6);
        __builtin_amdgcn_s_barrier();
        __builtin_amdgcn_s_setprio(1);
#pragma unroll
        for (int i = 0; i < 4; i++)
#pragma unroll
            for (int j = 0; j < 4; j++)
                accB[i][j] = __builtin_amdgcn_mfma_f32_16x16x32_bf16(af[i], bf[j], accB[i][j], 0, 0, 0);
        __builtin_amdgcn_s_setprio(0);
        __builtin_amdgcn_s_barrier();

        // ---- P3: GEMM1, K-half 1
#pragma unroll
        for (int i = 0; i < 4; i++) af[i] = *(const s8v*)&LA[aoff[1] + i * 1024];
#pragma unroll
        for (int j = 0; j < 4; j++) bf[j] = *(const s8v*)&LB1[boff[1] + j * 1024];
        stage_half(hb + 7);
        __builtin_amdgcn_s_barrier();
        __builtin_amdgcn_s_setprio(1);
#pragma unroll
        for (int i = 0; i < 4; i++)
#pragma unroll
            for (int j = 0; j < 4; j++)
                accA[i][j] = __builtin_amdgcn_mfma_f32_16x16x32_bf16(af[i], bf[j], accA[i][j], 0, 0, 0);
        __builtin_amdgcn_s_setprio(0);
        __builtin_amdgcn_s_barrier();

        // ---- P4: GEMM2, K-half 1
#pragma unroll
        for (int j = 0; j < 4; j++) bf[j] = *(const s8v*)&LB2[boff[1] + j * 1024];
        stage_half(hb + 8);
        __builtin_amdgcn_s_barrier();
        __builtin_amdgcn_s_setprio(1);
#pragma unroll
        for (int i = 0; i < 4; i++)
#pragma unroll
            for (int j = 0; j < 4; j++)
                accB[i][j] = __builtin_amdgcn_mfma_f32_16x16x32_bf16(af[i], bf[j], accB[i][j], 0, 0, 0);
        __builtin_amdgcn_s_setprio(0);
        // tile boundary: counted wait BEFORE the barrier (publishes writes)
        if (t < 14)       { asm volatile("s_waitcnt vmcnt(2)" ::: "memory"); }
        else if (t == 14) { asm volatile("s_waitcnt vmcnt(0)" ::: "memory"); }
        __builtin_amdgcn_s_barrier();
    }

    // epilogue: D layout col = lane&15, row = quad*4 + reg
#pragma unroll
    for (int i = 0; i < 4; i++) {
#pragma unroll
        for (int j = 0; j < 4; j++) {
#pragma unroll
            for (int r = 0; r < 4; r++) {
                int gm = m0 + wr * 64 + i * 16 + quad * 4 + r;
                int gn = n0 + wc * 64 + j * 16 + lo;
                float a = accA[i][j][r] + bias1[gn];
                float g = accB[i][j][r] + bias2[gn];
                C[(size_t)gm * 4096 + gn] = f2b(a * sigf(g));
            }
        }
    }
}

// ---------------------------------------------------------------------------
// R16: QKVG on the sk8 schedule (verified R7) — single-B, tile 256x128,
// NT=16 (K=1024), no split-K, grid (32,16) = 512 blocks = 2/CU (same
// block-overlap regime as ff8; fixes qkvg8d's 256-block 465-TF stall).
// 3 halves/tile (A0, A1, B), slot=h%6, 96 KB LDS. Ledger: end of tile t
// issued <=3t+6; vmcnt(2) completes <=3t+5 = tile t+1 reads; stage(3t+6)
// overwrites own slot0 after P2's 2nd barrier (safe, sk8 argument).
// Epilogue: per-1024-seg bias, sigmoid for n0>=3072, bf16 out.
__global__ __launch_bounds__(512, 1) void gemm_qn8(
    const unsigned short* __restrict__ A,   // [4096][1024] bf16 (xb)
    const unsigned short* __restrict__ BT,  // [4096][1024] bf16 (WTq)
    const float* __restrict__ b0, const float* __restrict__ b1,
    const float* __restrict__ b2, const float* __restrict__ b3,
    unsigned short* __restrict__ C)
{
    constexpr int NT = 16;
    __shared__ short Lds[6 * 8192];  // 96 KB

    const int tid  = threadIdx.x;
    const int ln   = tid & 63, wv = tid >> 6;
    const int wr   = wv >> 1, wc = wv & 1;
    const int quad = ln >> 4, lo = ln & 15;
    const int m0   = blockIdx.y * 256, n0 = blockIdx.x * 128;

    const int rowst = wv * 8 + (ln >> 3);
    const int cosrc = ((ln & 7) ^ (ln >> 3)) * 8;
    short* const ldst0 = &Lds[(wv * 8) * 64];

    f4 acc[4][4];
#pragma unroll
    for (int i = 0; i < 4; i++)
#pragma unroll
        for (int j = 0; j < 4; j++)
#pragma unroll
            for (int r = 0; r < 4; r++) acc[i][j][r] = 0.f;

    auto stage_half = [&](int h) {
        if (h >= 3 * NT) return;
        const int tt = h / 3, kind = h % 3, slot = h % 6;
        const unsigned short* gsrc;
        if (kind == 0)      gsrc = A  + (size_t)(m0 + rowst) * 1024 + tt * 64 + cosrc;
        else if (kind == 1) gsrc = A  + (size_t)(m0 + 128 + rowst) * 1024 + tt * 64 + cosrc;
        else                gsrc = BT + (size_t)(n0 + rowst) * 1024 + tt * 64 + cosrc;
        short* ldst = ldst0 + slot * 8192;
        GL2LDS(gsrc,                     ldst);
        GL2LDS(gsrc + (size_t)64 * 1024, ldst + 64 * 64);
    };

    int aoff[2], boff[2];
#pragma unroll
    for (int kh = 0; kh < 2; kh++) {
        const int sw = (((kh * 4 + quad) ^ (lo & 7)) * 8);
        aoff[kh] = (((wr & 1) * 64 + lo) * 64) + sw;
        boff[kh] = ((wc * 64 + lo) * 64) + sw;
    }
    const int slA = wr >> 1;  // kind 0/1

#pragma unroll
    for (int h = 0; h < 4; h++) stage_half(h);
    asm volatile("s_waitcnt vmcnt(2)" ::: "memory");
    __builtin_amdgcn_s_barrier();

    for (int t = 0; t < NT; t++) {
        const int base = (t & 1) * 3;
        const short* LA = &Lds[(base + slA) * 8192];
        const short* LB = &Lds[(base + 2) * 8192];
        s8v af[4], bf[4];

        // ---- P1: K-half 0
#pragma unroll
        for (int i = 0; i < 4; i++) af[i] = *(const s8v*)&LA[aoff[0] + i * 1024];
#pragma unroll
        for (int j = 0; j < 4; j++) bf[j] = *(const s8v*)&LB[boff[0] + j * 1024];
        stage_half(3 * t + 4);
        __builtin_amdgcn_s_barrier();
        __builtin_amdgcn_s_setprio(1);
#pragma unroll
        for (int i = 0; i < 4; i++)
#pragma unroll
            for (int j = 0; j < 4; j++)
                acc[i][j] = __builtin_amdgcn_mfma_f32_16x16x32_bf16(af[i], bf[j], acc[i][j], 0, 0, 0);
        __builtin_amdgcn_s_setprio(0);
        __builtin_amdgcn_s_barrier();

        // ---- P2: K-half 1
#pragma unroll
        for (int i = 0; i < 4; i++) af[i] = *(const s8v*)&LA[aoff[1] + i * 1024];
#pragma unroll
        for (int j = 0; j < 4; j++) bf[j] = *(const s8v*)&LB[boff[1] + j * 1024];
        stage_half(3 * t + 5);
        __builtin_amdgcn_s_barrier();
        __builtin_amdgcn_s_setprio(1);
#pragma unroll
        for (int i = 0; i < 4; i++)
#pragma unroll
            for (int j = 0; j < 4; j++)
                acc[i][j] = __builtin_amdgcn_mfma_f32_16x16x32_bf16(af[i], bf[j], acc[i][j], 0, 0, 0);
        __builtin_amdgcn_s_setprio(0);
        __builtin_amdgcn_s_barrier();

        // ---- tile end
        stage_half(3 * t + 6);
        if (t < NT - 2)       { asm volatile("s_waitcnt vmcnt(2)" ::: "memory"); }
        else if (t == NT - 2) { asm volatile("s_waitcnt vmcnt(0)" ::: "memory"); }
        __builtin_amdgcn_s_barrier();
    }

    // epilogue: per-1024-seg bias; sigmoid on G segment (n0 128-aligned,
    // tile never crosses a 1024 boundary)
    const int seg = n0 >> 10;
    const float* bp = (seg == 0) ? b0 : (seg == 1) ? b1 : (seg == 2) ? b2 : b3;
    const bool do_sig = (n0 >= 3072);
#pragma unroll
    for (int i = 0; i < 4; i++) {
#pragma unroll
        for (int j = 0; j < 4; j++) {
#pragma unroll
            for (int r = 0; r < 4; r++) {
                int gm = m0 + wr * 64 + i * 16 + quad * 4 + r;
                int gn = n0 + wc * 64 + j * 16 + lo;
                float v = acc[i][j][r] + bp[gn & 1023];
                if (do_sig) v = sigf(v);
                C[(size_t)gm * 4096 + gn] = f2b(v);
            }
        }
    }
}

// ---------------------------------------------------------------------------
// Split-K single-B 8-phase-style GEMM for Wf2 (N=1024, K=4096). Verified R7.
// Tile 256x128, grid (8,16,2). Ledger identical to gemm_qn8 with NT=32.
__global__ __launch_bounds__(512, 1) void gemm_sk8(
    const unsigned short* __restrict__ A,   // [4096][4096] bf16 (H1)
    const unsigned short* __restrict__ BT,  // [1024][4096] bf16 (Wf2T)
    float* __restrict__ P0, float* __restrict__ P1)
{
    constexpr int NT = 32;
    __shared__ short Lds[6 * 8192];  // 96 KB

    const int tid  = threadIdx.x;
    const int ln   = tid & 63, wv = tid >> 6;
    const int wr   = wv >> 1, wc = wv & 1;
    const int quad = ln >> 4, lo = ln & 15;
    const int m0   = blockIdx.y * 256, n0 = blockIdx.x * 128;
    const int kb   = blockIdx.z * 2048;
    float* const P = blockIdx.z ? P1 : P0;

    const int rowst = wv * 8 + (ln >> 3);
    const int cosrc = ((ln & 7) ^ (ln >> 3)) * 8;
    short* const ldst0 = &Lds[(wv * 8) * 64];

    f4 acc[4][4];
#pragma unroll
    for (int i = 0; i < 4; i++)
#pragma unroll
        for (int j = 0; j < 4; j++)
#pragma unroll
            for (int r = 0; r < 4; r++) acc[i][j][r] = 0.f;

    auto stage_half = [&](int h) {
        if (h >= 3 * NT) return;
        const int tt = h / 3, kind = h % 3, slot = h % 6;
        const unsigned short* gsrc;
        if (kind == 0)      gsrc = A  + (size_t)(m0 + rowst) * 4096 + kb + tt * 64 + cosrc;
        else if (kind == 1) gsrc = A  + (size_t)(m0 + 128 + rowst) * 4096 + kb + tt * 64 + cosrc;
        else                gsrc = BT + (size_t)(n0 + rowst) * 4096 + kb + tt * 64 + cosrc;
        short* ldst = ldst0 + slot * 8192;
        GL2LDS(gsrc,                     ldst);
        GL2LDS(gsrc + (size_t)64 * 4096, ldst + 64 * 64);
    };

    int aoff[2], boff[2];
#pragma unroll
    for (int kh = 0; kh < 2; kh++) {
        const int sw = (((kh * 4 + quad) ^ (lo & 7)) * 8);
        aoff[kh] = (((wr & 1) * 64 + lo) * 64) + sw;
        boff[kh] = ((wc * 64 + lo) * 64) + sw;
    }
    const int slA = wr >> 1;  // kind 0/1

#pragma unroll
    for (int h = 0; h < 4; h++) stage_half(h);
    asm volatile("s_waitcnt vmcnt(2)" ::: "memory");
    __builtin_amdgcn_s_barrier();

    for (int t = 0; t < NT; t++) {
        const int base = (t & 1) * 3;
        const short* LA = &Lds[(base + slA) * 8192];
        const short* LB = &Lds[(base + 2) * 8192];
        s8v af[4], bf[4];

        // ---- P1: K-half 0
#pragma unroll
        for (int i = 0; i < 4; i++) af[i] = *(const s8v*)&LA[aoff[0] + i * 1024];
#pragma unroll
        for (int j = 0; j < 4; j++) bf[j] = *(const s8v*)&LB[boff[0] + j * 1024];
        stage_half(3 * t + 4);
        __builtin_amdgcn_s_barrier();
        __builtin_amdgcn_s_setprio(1);
#pragma unroll
        for (int i = 0; i < 4; i++)
#pragma unroll
            for (int j = 0; j < 4; j++)
                acc[i][j] = __builtin_amdgcn_mfma_f32_16x16x32_bf16(af[i], bf[j], acc[i][j], 0, 0, 0);
        __builtin_amdgcn_s_setprio(0);
        __builtin_amdgcn_s_barrier();

        // ---- P2: K-half 1
#pragma unroll
        for (int i = 0; i < 4; i++) af[i] = *(const s8v*)&LA[aoff[1] + i * 1024];
#pragma unroll
        for (int j = 0; j < 4; j++) bf[j] = *(const s8v*)&LB[boff[1] + j * 1024];
        stage_half(3 * t + 5);
        __builtin_amdgcn_s_barrier();
        __builtin_amdgcn_s_setprio(1);
#pragma unroll
        for (int i = 0; i < 4; i++)
#pragma unroll
            for (int j = 0; j < 4; j++)
                acc[i][j] = __builtin_amdgcn_mfma_f32_16x16x32_bf16(af[i], bf[j], acc[i][j], 0, 0, 0);
        __builtin_amdgcn_s_setprio(0);
        __builtin_amdgcn_s_barrier();

        // ---- tile end
        stage_half(3 * t + 6);
        if (t < NT - 2)       { asm volatile("s_waitcnt vmcnt(2)" ::: "memory"); }
        else if (t == NT - 2) { asm volatile("s_waitcnt vmcnt(0)" ::: "memory"); }
        __builtin_amdgcn_s_barrier();
    }

#pragma unroll
    for (int i = 0; i < 4; i++) {
#pragma unroll
        for (int j = 0; j < 4; j++) {
#pragma unroll
            for (int r = 0; r < 4; r++) {
                int gm = m0 + wr * 64 + i * 16 + quad * 4 + r;
                int gn = n0 + wc * 64 + j * 16 + lo;
                P[(size_t)gm * 1024 + gn] = acc[i][j][r];
            }
        }
    }
}

// ---------------------------------------------------------------------------
// Flash attention, fixed-shift softmax. R2-verified config: 16 q/wave,
// KVBLK=32, grid 16x64 = 1024 blocks = 4/CU.
__global__ __launch_bounds__(256) void attn_kernel(
    const unsigned short* __restrict__ QKVG, const float* __restrict__ bias,
    unsigned short* __restrict__ ctx)
{
    __shared__ short Ks[32 * 72];     // [kv][d]
    __shared__ short Vt[64 * 48];     // [d][perm kv]
    __shared__ short Ps[4][16 * 40];  // per-wave P [q][perm kv]

    const int tid = threadIdx.x;
    const int lane = tid & 63, wave = tid >> 6;
    const int quad = lane >> 4, lo = lane & 15;
    const int bh = blockIdx.y;
    const int b = bh >> 4, h = bh & 15;
    const int q0 = blockIdx.x * 64 + wave * 16;
    const size_t base  = (size_t)b * NS * 4096 + (size_t)h * 64;
    const size_t baseK = base + 1024, baseV = base + 2048;
    constexpr float c1 = 0.125f * 1.44269504f;

    s8v aq0 = *(const s8v*)(QKVG + base + (size_t)(q0 + lo) * 4096 + quad * 8);
    s8v aq1 = *(const s8v*)(QKVG + base + (size_t)(q0 + lo) * 4096 + 32 + quad * 8);

    f4 accO[4];
    float l_r[4];
#pragma unroll
    for (int r = 0; r < 4; r++) {
        l_r[r] = 0.f;
#pragma unroll
        for (int j = 0; j < 4; j++) accO[j][r] = 0.f;
    }

    const int skv = tid >> 3, sd8 = (tid & 7) * 8;
    const int vkv = tid & 31, vd8 = (tid >> 5) * 8;
    const int pvk = 2 * (vkv & 15) + (vkv >> 4);

    s8v kk = *(const s8v*)(QKVG + baseK + (size_t)skv * 4096 + sd8);
    s8v vv = *(const s8v*)(QKVG + baseV + (size_t)vkv * 4096 + vd8);

    for (int kv0 = 0; kv0 < NS; kv0 += 32) {
        *(s8v*)&Ks[skv * 72 + sd8] = kk;
#pragma unroll
        for (int i = 0; i < 8; i++) Vt[(vd8 + i) * 48 + pvk] = (short)vv[i];
        __syncthreads();

        s8v kkn = kk, vvn = vv;
        if (kv0 + 32 < NS) {
            kkn = *(const s8v*)(QKVG + baseK + (size_t)(kv0 + 32 + skv) * 4096 + sd8);
            vvn = *(const s8v*)(QKVG + baseV + (size_t)(kv0 + 32 + vkv) * 4096 + vd8);
        }

        f4 sc[2];
#pragma unroll
        for (int cb = 0; cb < 2; cb++) {
            s8v bk0 = *(const s8v*)&Ks[(cb * 16 + lo) * 72 + quad * 8];
            s8v bk1 = *(const s8v*)&Ks[(cb * 16 + lo) * 72 + 32 + quad * 8];
            f4 z;
#pragma unroll
            for (int r = 0; r < 4; r++) z[r] = 0.f;
            z = __builtin_amdgcn_mfma_f32_16x16x32_bf16(aq0, bk0, z, 0, 0, 0);
            sc[cb] = __builtin_amdgcn_mfma_f32_16x16x32_bf16(aq1, bk1, z, 0, 0, 0);
        }

        int* PsI = (int*)&Ps[wave][0];
#pragma unroll
        for (int r = 0; r < 4; r++) {
            int qrow = q0 + quad * 4 + r;
            const float* bp = &bias[(size_t)qrow * NS + kv0];
            float p0 = exp2f(sc[0][r] * c1 + bp[lo]);
            float p1 = exp2f(sc[1][r] * c1 + bp[16 + lo]);
            l_r[r] += p0 + p1;
            unsigned int pk = (unsigned int)f2b(p0) | ((unsigned int)f2b(p1) << 16);
            PsI[(quad * 4 + r) * 20 + lo] = (int)pk;
        }
        s8v pf = *(const s8v*)&Ps[wave][lo * 40 + quad * 8];
#pragma unroll
        for (int j = 0; j < 4; j++) {
            s8v bv = *(const s8v*)&Vt[(j * 16 + lo) * 48 + quad * 8];
            accO[j] = __builtin_amdgcn_mfma_f32_16x16x32_bf16(pf, bv, accO[j], 0, 0, 0);
        }
        __syncthreads();
        kk = kkn; vv = vvn;
    }

#pragma unroll
    for (int r = 0; r < 4; r++) {
        float l = l_r[r];
#pragma unroll
        for (int d = 1; d < 16; d <<= 1) l += __shfl_xor(l, d, 64);
        l_r[r] = 1.f / l;
    }
#pragma unroll
    for (int j = 0; j < 4; j++)
#pragma unroll
        for (int r = 0; r < 4; r++) {
            int qrow = q0 + quad * 4 + r;
            ctx[((size_t)b * NS + qrow) * 1024 + h * 64 + j * 16 + lo] = f2b(accO[j][r] * l_r[r]);
        }
}

// ---------------------------------------------------------------------------
// LayerNorm over last dim (1024). X bf16 in, bf16 out (ln1 path).
__global__ __launch_bounds__(256) void ln_kernel(
    const unsigned short* __restrict__ X, const float* __restrict__ g,
    const float* __restrict__ bb, unsigned short* __restrict__ out)
{
    const int row = blockIdx.x;
    const unsigned short* xr = X + (size_t)row * NE;
    s4v xv = *(const s4v*)(xr + threadIdx.x * 4);
    float v[4], s = 0.f, ss = 0.f;
#pragma unroll
    for (int i = 0; i < 4; i++) {
        v[i] = b2f((unsigned short)xv[i]);
        s += v[i]; ss += v[i] * v[i];
    }
#pragma unroll
    for (int d = 1; d < 64; d <<= 1) { s += __shfl_xor(s, d, 64); ss += __shfl_xor(ss, d, 64); }
    __shared__ float red[8];
    int wave = threadIdx.x >> 6, lane = threadIdx.x & 63;
    if (lane == 0) { red[wave] = s; red[4 + wave] = ss; }
    __syncthreads();
    s  = red[0] + red[1] + red[2] + red[3];
    ss = red[4] + red[5] + red[6] + red[7];
    float mu = s * (1.f / NE);
    float var = ss * (1.f / NE) - mu * mu;
    float rstd = rsqrtf(fmaxf(var, 0.f) + 1e-6f);
#pragma unroll
    for (int i = 0; i < 4; i++) {
        int c = threadIdx.x * 4 + i;
        float o = (v[i] - mu) * rstd * g[c] + bb[c];
        out[(size_t)row * NE + c] = f2b(o);
    }
}

// ---------------------------------------------------------------------------
// Fused split-K reduce + residual + bias + LayerNorm (ln2 path):
// t = X1 + P0 + P1 + bf2;  out = LN(t) (f32).
__global__ __launch_bounds__(256) void ln2red_kernel(
    const unsigned short* __restrict__ X1,
    const float* __restrict__ P0, const float* __restrict__ P1,
    const float* __restrict__ bf2,
    const float* __restrict__ g, const float* __restrict__ bb,
    float* __restrict__ out)
{
    const int row = blockIdx.x;
    const size_t rb = (size_t)row * NE;
    s4v xv = *(const s4v*)(X1 + rb + threadIdx.x * 4);
    f4 p0 = *(const f4*)(P0 + rb + threadIdx.x * 4);
    f4 p1 = *(const f4*)(P1 + rb + threadIdx.x * 4);
    float v[4], s = 0.f, ss = 0.f;
#pragma unroll
    for (int i = 0; i < 4; i++) {
        int c = threadIdx.x * 4 + i;
        v[i] = b2f((unsigned short)xv[i]) + p0[i] + p1[i] + bf2[c];
        s += v[i]; ss += v[i] * v[i];
    }
#pragma unroll
    for (int d = 1; d < 64; d <<= 1) { s += __shfl_xor(s, d, 64); ss += __shfl_xor(ss, d, 64); }
    __shared__ float red[8];
    int wave = threadIdx.x >> 6, lane = threadIdx.x & 63;
    if (lane == 0) { red[wave] = s; red[4 + wave] = ss; }
    __syncthreads();
    s  = red[0] + red[1] + red[2] + red[3];
    ss = red[4] + red[5] + red[6] + red[7];
    float mu = s * (1.f / NE);
    float var = ss * (1.f / NE) - mu * mu;
    float rstd = rsqrtf(fmaxf(var, 0.f) + 1e-6f);
#pragma unroll
    for (int i = 0; i < 4; i++) {
        int c = threadIdx.x * 4 + i;
        out[rb + c] = (v[i] - mu) * rstd * g[c] + bb[c];
    }
}

// ---------------------------------------------------------------------------
// Workspace map (peak 78 MB):
//   [0,8)   xb -> T1
//   [8,16)  WTqkvg -> Cx -> X1
//   [16,18) WoT   [18,26) Wf1T   [26,34) WfgT   [34,42) Wf2T
//   [42,46) biasP (fp32, log2-domain, shift folded)
//   [46,78) QKVG -> H1
//   Wf2 split-K partials: P0 -> [18,34) (Wf1T/WfgT, dead after FF GEMM);
//   P1 -> d_out (f32 16MB, overwritten by ln2red afterwards).
extern "C" void kernel_launch(void* const* d_in, const int* in_sizes, int n_in,
                              void* d_out, int out_size, void* d_ws, size_t ws_size,
                              hipStream_t stream)
{
    const float* x    = (const float*)d_in[0];
    const float* pe   = (const float*)d_in[1];
    const float* Wq   = (const float*)d_in[2];
    const float* bq   = (const float*)d_in[3];
    const float* Wk   = (const float*)d_in[4];
    const float* bk   = (const float*)d_in[5];
    const float* Wv   = (const float*)d_in[6];
    const float* bv   = (const float*)d_in[7];
    const float* Wo   = (const float*)d_in[8];
    const float* bo   = (const float*)d_in[9];
    const float* Wg   = (const float*)d_in[10];
    const float* bg   = (const float*)d_in[11];
    const float* Wf1  = (const float*)d_in[12];
    const float* bf1  = (const float*)d_in[13];
    const float* Wfg  = (const float*)d_in[14];
    const float* bfg  = (const float*)d_in[15];
    const float* Wf2  = (const float*)d_in[16];
    const float* bf2  = (const float*)d_in[17];
    const float* ln1g = (const float*)d_in[18];
    const float* ln1b = (const float*)d_in[19];
    const float* ln2g = (const float*)d_in[20];
    const float* ln2b = (const float*)d_in[21];

    char* ws = (char*)d_ws;
    unsigned short* xb    = (unsigned short*)ws;                         // [0,8)
    unsigned short* WTq   = (unsigned short*)(ws + ( 8ull << 20));       // [8,16)
    unsigned short* WoT   = (unsigned short*)(ws + (16ull << 20));       // [16,18)
    unsigned short* Wf1T  = (unsigned short*)(ws + (18ull << 20));       // [18,26)
    unsigned short* WfgT  = (unsigned short*)(ws + (26ull << 20));       // [26,34)
    unsigned short* Wf2T  = (unsigned short*)(ws + (34ull << 20));       // [34,42)
    float*          biasP = (float*)(ws + (42ull << 20));                // [42,46)
    unsigned short* QKVG  = (unsigned short*)(ws + (46ull << 20));       // [46,78)
    unsigned short* T1 = xb;
    unsigned short* Cx = WTq;
    unsigned short* X1 = WTq;
    unsigned short* H1 = QKVG;
    float* P0 = (float*)(ws + (18ull << 20));   // aliases Wf1T/WfgT (dead)
    float* P1 = (float*)d_out;                  // overwritten by ln2red

    dim3 blk(256);

    // fused prep: cvt_x | 5x ExE WT | Wf1T/WfgT | Wf2T | posmean
    prep_kernel<<<dim3(2048 + 1280 + 2048 + 1024 + 4096), blk, 0, stream>>>(
        x, xb, Wq, Wk, Wv, Wg, Wo, WTq, WoT,
        Wf1, Wfg, Wf2, Wf1T, WfgT, Wf2T, pe, biasP);

    // fused QKVG: sk8-schedule single-B, 256x128 tile, 512 blocks = 2/CU
    gemm_qn8<<<dim3(32, 16), dim3(512), 0, stream>>>(
        xb, WTq, bq, bk, bv, bg, QKVG);

    attn_kernel<<<dim3(NS / 64, NB * NH), blk, 0, stream>>>(QKVG, biasP, Cx);

    // T1 = xb + G * (Cx@Wo + bo)   (T1 aliases xb: same-idx read-then-write)
    gemm_gate<2><<<dim3(8, 64), blk, 0, stream>>>(
        Cx, WoT, bo, xb, QKVG + 3072, T1, NM, NE, NE);
    ln_kernel<<<dim3(NM), blk, 0, stream>>>(T1, ln1g, ln1b, X1);

    // fused FF: dedicated 8-phase kernel (R6-verified source)
    gemm_ff8<<<dim3(NFF / 128, NM / 256), dim3(512), 0, stream>>>(
        X1, Wf1T, WfgT, bf1, bfg, H1);

    // Wf2: split-K=2 8-phase-style, f32 partials
    gemm_sk8<<<dim3(8, 16, 2), dim3(512), 0, stream>>>(H1, Wf2T, P0, P1);

    // fused reduce + residual + bias + LN2 -> d_out (f32)
    ln2red_kernel<<<dim3(NM), blk, 0, stream>>>(
        X1, P0, P1, bf2, ln2g, ln2b, (float*)d_out);
}

// Round 10
// 419.123 us; speedup vs baseline: 1.0418x; 1.0418x over previous
//
#include <hip/hip_runtime.h>

// Problem constants
constexpr int NB = 4, NS = 1024, NE = 1024, NH = 16, NFF = 4096;
constexpr int NM = NB * NS; // 4096 token rows

typedef short s8v __attribute__((ext_vector_type(8)));
typedef short s4v __attribute__((ext_vector_type(4)));
typedef float f4  __attribute__((ext_vector_type(4)));

__device__ __forceinline__ float b2f(unsigned short u) {
    union { unsigned int i; float f; } v; v.i = ((unsigned int)u) << 16; return v.f;
}
__device__ __forceinline__ unsigned short f2b(float f) {
    union { float f; unsigned int i; } v; v.f = f;
    unsigned int r = v.i + 0x7FFFu + ((v.i >> 16) & 1u);
    return (unsigned short)(r >> 16);
}
__device__ __forceinline__ float sigf(float x) { return 1.f / (1.f + __expf(-x)); }

#define GL2LDS(g, l) __builtin_amdgcn_global_load_lds( \
    (const __attribute__((address_space(1))) void*)(g), \
    (__attribute__((address_space(3))) void*)(l), 16, 0, 0)

// ---------------------------------------------------------------------------
// Fused prep: cvt_x + 5x(ExE transpose) + 2x(ExFF transpose) + 1x(FFxE
// transpose) + posmean, one launch.
__device__ __forceinline__ void cvt_t_tile(
    const float* __restrict__ W, unsigned short* __restrict__ WT,
    int K, int N, int bx, int by, int t, unsigned short L[64][72])
{
    const int k0 = by * 64, n0 = bx * 64;
    const int r = t >> 4, c4 = (t & 15) * 4;
#pragma unroll
    for (int p = 0; p < 4; p++) {
        int k = r + p * 16;
        f4 v = *(const f4*)&W[(size_t)(k0 + k) * N + n0 + c4];
#pragma unroll
        for (int i = 0; i < 4; i++) L[c4 + i][k] = f2b(v[i]);
    }
    __syncthreads();
    const int n = t >> 2, kc = (t & 3) * 16;
    s8v o0, o1;
#pragma unroll
    for (int i = 0; i < 8; i++) { o0[i] = (short)L[n][kc + i]; o1[i] = (short)L[n][kc + 8 + i]; }
    unsigned short* dst = WT + (size_t)(n0 + n) * K + k0 + kc;
    *(s8v*)dst = o0; *(s8v*)(dst + 8) = o1;
}

__global__ __launch_bounds__(256) void prep_kernel(
    const float* __restrict__ x, unsigned short* __restrict__ xb,
    const float* Wq, const float* Wk, const float* Wv, const float* Wg,
    const float* Wo,
    unsigned short* WTq, unsigned short* WoT,
    const float* Wf1, const float* Wfg, const float* Wf2,
    unsigned short* Wf1T, unsigned short* WfgT, unsigned short* Wf2T,
    const float* __restrict__ pe, float* __restrict__ biasP)
{
    __shared__ unsigned short L[64][72];
    const int t = threadIdx.x;
    int bid = blockIdx.x;

    if (bid < 2048) {  // ---- cvt_x: fp32 -> bf16, 4096x1024
        size_t i = ((size_t)bid * 256 + t) * 8;
        f4 v0 = *(const f4*)(x + i), v1 = *(const f4*)(x + i + 4);
        s8v o;
#pragma unroll
        for (int j = 0; j < 4; j++) { o[j] = (short)f2b(v0[j]); o[4 + j] = (short)f2b(v1[j]); }
        *(s8v*)(xb + i) = o;
        return;
    }
    bid -= 2048;
    if (bid < 1280) {  // ---- 5x ExE transpose
        int z = bid >> 8, rem = bid & 255;
        const float* W = (z == 0) ? Wq : (z == 1) ? Wk : (z == 2) ? Wv : (z == 3) ? Wg : Wo;
        unsigned short* WT = (z == 4) ? WoT : WTq + (size_t)z * 1024 * 1024;
        cvt_t_tile(W, WT, 1024, 1024, rem & 15, rem >> 4, t, L);
        return;
    }
    bid -= 1280;
    if (bid < 2048) {  // ---- Wf1 / Wfg transpose (K=1024, N=4096)
        int z = bid >> 10, rem = bid & 1023;
        cvt_t_tile(z ? Wfg : Wf1, z ? WfgT : Wf1T, 1024, 4096, rem & 63, rem >> 6, t, L);
        return;
    }
    bid -= 2048;
    if (bid < 1024) {  // ---- Wf2 transpose (K=4096, N=1024)
        cvt_t_tile(Wf2, Wf2T, 4096, 1024, bid & 15, bid >> 4, t, L);
        return;
    }
    bid -= 1024;
    {  // ---- posmean
        int idx = bid * 256 + t;
        const float* p = pe + (size_t)idx * 8;
        f4 v0 = *(const f4*)p, v1 = *(const f4*)(p + 4);
        float s = 0.f;
#pragma unroll
        for (int i = 0; i < 4; i++) s += v0[i] + v1[i];
        biasP[idx] = (s * 0.125f - 8.0f) * 1.44269504f;
    }
}

// ---------------------------------------------------------------------------
// MFMA GEMM, BT layout, 2-phase. Kept only for GATE_RES.
// OCCUPANCY RULE (R4): grid must stay >= 512 blocks.
template <int TM>
__global__ __launch_bounds__(256) void gemm_gate(
    const unsigned short* __restrict__ A,
    const unsigned short* __restrict__ BT,
    const float* b0p,
    const unsigned short* ex1, const unsigned short* ex2,
    unsigned short* C, int M, int N, int K)
{
    constexpr int AR = 32 * TM;
    __shared__ short As0[AR * 32], As1[AR * 32];
    __shared__ short Bs0[128 * 32], Bs1[128 * 32];

    const int tid  = threadIdx.x;
    const int m0   = blockIdx.y * AR;
    const int n0   = blockIdx.x * 128;
    const int lane = tid & 63;
    const int wave = tid >> 6;
    const int wm   = (wave >> 1) * (16 * TM), wn = (wave & 1) * 64;
    const int quad = lane >> 4, lo = lane & 15;
    const int lrow = lane >> 2;
    const int lcol = (((lane & 3) ^ ((lane >> 4) & 3))) * 8;
    const int rcol = ((quad ^ ((lo >> 2) & 3))) * 8;

    f4 acc[TM][4];
#pragma unroll
    for (int i = 0; i < TM; i++)
#pragma unroll
        for (int j = 0; j < 4; j++)
#pragma unroll
            for (int r = 0; r < 4; r++) acc[i][j][r] = 0.f;

    const unsigned short* ga = A  + (size_t)(m0 + wave * (AR / 4) + lrow) * K + lcol;
    const unsigned short* gb = BT + (size_t)(n0 + wave * 32 + lrow) * K + lcol;
    short* lA0  = &As0[(wave * (AR / 4)) * 32];
    short* lA1  = &As1[(wave * (AR / 4)) * 32];
    short* lB00 = &Bs0[(wave * 32) * 32];
    short* lB01 = &Bs0[(wave * 32 + 16) * 32];
    short* lB10 = &Bs1[(wave * 32) * 32];
    short* lB11 = &Bs1[(wave * 32 + 16) * 32];

    for (int k0 = 0; k0 < K; k0 += 64) {
#pragma unroll
        for (int t = 0; t < TM / 2; t++) {
            GL2LDS(ga + k0 +      (size_t)t * 16 * K, lA0 + t * 16 * 32);
            GL2LDS(ga + k0 + 32 + (size_t)t * 16 * K, lA1 + t * 16 * 32);
        }
        GL2LDS(gb + k0,               lB00);
        GL2LDS(gb + k0 + 16 * K,      lB01);
        GL2LDS(gb + k0 + 32,          lB10);
        GL2LDS(gb + k0 + 32 + 16 * K, lB11);
        __syncthreads();

        s8v af[TM], bf[4];
#pragma unroll
        for (int i = 0; i < TM; i++)
            af[i] = *(const s8v*)&As0[(wm + i * 16 + lo) * 32 + rcol];
#pragma unroll
        for (int j = 0; j < 4; j++)
            bf[j] = *(const s8v*)&Bs0[(wn + j * 16 + lo) * 32 + rcol];
#pragma unroll
        for (int i = 0; i < TM; i++)
#pragma unroll
            for (int j = 0; j < 4; j++)
                acc[i][j] = __builtin_amdgcn_mfma_f32_16x16x32_bf16(af[i], bf[j], acc[i][j], 0, 0, 0);
#pragma unroll
        for (int i = 0; i < TM; i++)
            af[i] = *(const s8v*)&As1[(wm + i * 16 + lo) * 32 + rcol];
#pragma unroll
        for (int j = 0; j < 4; j++)
            bf[j] = *(const s8v*)&Bs1[(wn + j * 16 + lo) * 32 + rcol];
#pragma unroll
        for (int i = 0; i < TM; i++)
#pragma unroll
            for (int j = 0; j < 4; j++)
                acc[i][j] = __builtin_amdgcn_mfma_f32_16x16x32_bf16(af[i], bf[j], acc[i][j], 0, 0, 0);
        __syncthreads();
    }

#pragma unroll
    for (int i = 0; i < TM; i++) {
#pragma unroll
        for (int j = 0; j < 4; j++) {
#pragma unroll
            for (int r = 0; r < 4; r++) {
                int gm = m0 + wm + i * 16 + quad * 4 + r;
                int gn = n0 + wn + j * 16 + lo;
                size_t idx = (size_t)gm * N + gn;
                float v = acc[i][j][r] + b0p[gn];
                v = b2f(ex1[idx]) + b2f(ex2[(size_t)gm * 4096 + gn]) * v;
                C[idx] = f2b(v);
            }
        }
    }
}

// ---------------------------------------------------------------------------
// 8-phase fused FF GEMM — DEDICATED kernel, R6/R8-verified (75.3-76.7 us,
// MfmaUtil 37%, conflicts 0, ~913 TF dual). DO NOT merge into a template
// (R7: co-compiled variant stretched it to 97.4 us).
__global__ __launch_bounds__(512, 1) void gemm_ff8(
    const unsigned short* __restrict__ A,
    const unsigned short* __restrict__ B1T,
    const unsigned short* __restrict__ B2T,
    const float* __restrict__ bias1, const float* __restrict__ bias2,
    unsigned short* __restrict__ C)
{
    __shared__ short Lds[8 * 8192];  // 128 KB

    const int tid  = threadIdx.x;
    const int ln   = tid & 63, wv = tid >> 6;
    const int wr   = wv >> 1, wc = wv & 1;      // wave grid 4M x 2N
    const int quad = ln >> 4, lo = ln & 15;
    const int m0   = blockIdx.y * 256, n0 = blockIdx.x * 128;

    const int rowst = wv * 8 + (ln >> 3);
    const int cosrc = ((ln & 7) ^ (ln >> 3)) * 8;
    short* const ldst0 = &Lds[(wv * 8) * 64];

    f4 accA[4][4], accB[4][4];
#pragma unroll
    for (int i = 0; i < 4; i++)
#pragma unroll
        for (int j = 0; j < 4; j++)
#pragma unroll
            for (int r = 0; r < 4; r++) { accA[i][j][r] = 0.f; accB[i][j][r] = 0.f; }

    auto stage_half = [&](int h) {
        if (h >= 64) return;
        const int tt = h >> 2, kind = h & 3, slot = h & 7;
        const unsigned short* gsrc;
        if (kind == 0)      gsrc = A   + (size_t)(m0 + rowst) * 1024 + tt * 64 + cosrc;
        else if (kind == 1) gsrc = A   + (size_t)(m0 + 128 + rowst) * 1024 + tt * 64 + cosrc;
        else if (kind == 2) gsrc = B1T + (size_t)(n0 + rowst) * 1024 + tt * 64 + cosrc;
        else                gsrc = B2T + (size_t)(n0 + rowst) * 1024 + tt * 64 + cosrc;
        short* ldst = ldst0 + slot * 8192;
        GL2LDS(gsrc,                     ldst);
        GL2LDS(gsrc + (size_t)64 * 1024, ldst + 64 * 64);
    };

    int aoff[2], boff[2];
#pragma unroll
    for (int kh = 0; kh < 2; kh++) {
        const int sw = (((kh * 4 + quad) ^ (lo & 7)) * 8);
        aoff[kh] = (((wr & 1) * 64 + lo) * 64) + sw;
        boff[kh] = ((wc * 64 + lo) * 64) + sw;
    }
    const int slA = wr >> 1;  // which A half this wave reads

    // prologue: halves 0..4 in flight; complete 0..3 (tile 0), allow half 4.
#pragma unroll
    for (int h = 0; h < 5; h++) stage_half(h);
    asm volatile("s_waitcnt vmcnt(2)" ::: "memory");
    __builtin_amdgcn_s_barrier();

    for (int t = 0; t < 16; t++) {
        const int p4 = (t & 1) * 4;
        const short* LA  = &Lds[(p4 + slA) * 8192];
        const short* LB1 = &Lds[(p4 + 2) * 8192];
        const short* LB2 = &Lds[(p4 + 3) * 8192];
        const int hb = 4 * t;
        s8v af[4], bf[4];

        // ---- P1: GEMM1 (Wf1), K-half 0
#pragma unroll
        for (int i = 0; i < 4; i++) af[i] = *(const s8v*)&LA[aoff[0] + i * 1024];
#pragma unroll
        for (int j = 0; j < 4; j++) bf[j] = *(const s8v*)&LB1[boff[0] + j * 1024];
        stage_half(hb + 5);
        __builtin_amdgcn_s_barrier();
        __builtin_amdgcn_s_setprio(1);
#pragma unroll
        for (int i = 0; i < 4; i++)
#pragma unroll
            for (int j = 0; j < 4; j++)
                accA[i][j] = __builtin_amdgcn_mfma_f32_16x16x32_bf16(af[i], bf[j], accA[i][j], 0, 0, 0);
        __builtin_amdgcn_s_setprio(0);
        __builtin_amdgcn_s_barrier();

        // ---- P2: GEMM2 (Wfg), K-half 0 (reuse af)
#pragma unroll
        for (int j = 0; j < 4; j++) bf[j] = *(const s8v*)&LB2[boff[0] + j * 1024];
        stage_half(hb + 6);
        __builtin_amdgcn_s_barrier();
        __builtin_amdgcn_s_setprio(1);
#pragma unroll
        for (int i = 0; i < 4; i++)
#pragma unroll
            for (int j = 0; j < 4; j++)
                accB[i][j] = __builtin_amdgcn_mfma_f32_16x16x32_bf16(af[i], bf[j], accB[i][j], 0, 0, 0);
        __builtin_amdgcn_s_setprio(0);
        __builtin_amdgcn_s_barrier();

        // ---- P3: GEMM1, K-half 1
#pragma unroll
        for (int i = 0; i < 4; i++) af[i] = *(const s8v*)&LA[aoff[1] + i * 1024];
#pragma unroll
        for (int j = 0; j < 4; j++) bf[j] = *(const s8v*)&LB1[boff[1] + j * 1024];
        stage_half(hb + 7);
        __builtin_amdgcn_s_barrier();
        __builtin_amdgcn_s_setprio(1);
#pragma unroll
        for (int i = 0; i < 4; i++)
#pragma unroll
            for (int j = 0; j < 4; j++)
                accA[i][j] = __builtin_amdgcn_mfma_f32_16x16x32_bf16(af[i], bf[j], accA[i][j], 0, 0, 0);
        __builtin_amdgcn_s_setprio(0);
        __builtin_amdgcn_s_barrier();

        // ---- P4: GEMM2, K-half 1
#pragma unroll
        for (int j = 0; j < 4; j++) bf[j] = *(const s8v*)&LB2[boff[1] + j * 1024];
        stage_half(hb + 8);
        __builtin_amdgcn_s_barrier();
        __builtin_amdgcn_s_setprio(1);
#pragma unroll
        for (int i = 0; i < 4; i++)
#pragma unroll
            for (int j = 0; j < 4; j++)
                accB[i][j] = __builtin_amdgcn_mfma_f32_16x16x32_bf16(af[i], bf[j], accB[i][j], 0, 0, 0);
        __builtin_amdgcn_s_setprio(0);
        // tile boundary: counted wait BEFORE the barrier (publishes writes)
        if (t < 14)       { asm volatile("s_waitcnt vmcnt(2)" ::: "memory"); }
        else if (t == 14) { asm volatile("s_waitcnt vmcnt(0)" ::: "memory"); }
        __builtin_amdgcn_s_barrier();
    }

    // epilogue: D layout col = lane&15, row = quad*4 + reg
#pragma unroll
    for (int i = 0; i < 4; i++) {
#pragma unroll
        for (int j = 0; j < 4; j++) {
#pragma unroll
            for (int r = 0; r < 4; r++) {
                int gm = m0 + wr * 64 + i * 16 + quad * 4 + r;
                int gn = n0 + wc * 64 + j * 16 + lo;
                float a = accA[i][j][r] + bias1[gn];
                float g = accB[i][j][r] + bias2[gn];
                C[(size_t)gm * 4096 + gn] = f2b(a * sigf(g));
            }
        }
    }
}

// ---------------------------------------------------------------------------
// R17: QKVG as a VERBATIM clone of gemm_ff8 (same names, same loop text) —
// only diffs: n0 = blockIdx.x*256, and the epilogue (per-seg bias +
// conditional sigmoid + dual-quadrant store). Called with B1T=WTq,
// B2T=WTq+128*1024 exactly like R7's gemm_dual8, which hit ~40 us (inferred
// from totals). Grid 16x16 = 256 blocks. If this rolls badly again, the
// lottery conclusion stands and attention is next.
__global__ __launch_bounds__(512, 1) void gemm_qkvgf(
    const unsigned short* __restrict__ A,
    const unsigned short* __restrict__ B1T,
    const unsigned short* __restrict__ B2T,
    const float* __restrict__ bias1, const float* __restrict__ bias2,
    const float* __restrict__ bias3, const float* __restrict__ bias4,
    unsigned short* __restrict__ C)
{
    __shared__ short Lds[8 * 8192];  // 128 KB

    const int tid  = threadIdx.x;
    const int ln   = tid & 63, wv = tid >> 6;
    const int wr   = wv >> 1, wc = wv & 1;      // wave grid 4M x 2N
    const int quad = ln >> 4, lo = ln & 15;
    const int m0   = blockIdx.y * 256, n0 = blockIdx.x * 256;

    const int rowst = wv * 8 + (ln >> 3);
    const int cosrc = ((ln & 7) ^ (ln >> 3)) * 8;
    short* const ldst0 = &Lds[(wv * 8) * 64];

    f4 accA[4][4], accB[4][4];
#pragma unroll
    for (int i = 0; i < 4; i++)
#pragma unroll
        for (int j = 0; j < 4; j++)
#pragma unroll
            for (int r = 0; r < 4; r++) { accA[i][j][r] = 0.f; accB[i][j][r] = 0.f; }

    auto stage_half = [&](int h) {
        if (h >= 64) return;
        const int tt = h >> 2, kind = h & 3, slot = h & 7;
        const unsigned short* gsrc;
        if (kind == 0)      gsrc = A   + (size_t)(m0 + rowst) * 1024 + tt * 64 + cosrc;
        else if (kind == 1) gsrc = A   + (size_t)(m0 + 128 + rowst) * 1024 + tt * 64 + cosrc;
        else if (kind == 2) gsrc = B1T + (size_t)(n0 + rowst) * 1024 + tt * 64 + cosrc;
        else                gsrc = B2T + (size_t)(n0 + rowst) * 1024 + tt * 64 + cosrc;
        short* ldst = ldst0 + slot * 8192;
        GL2LDS(gsrc,                     ldst);
        GL2LDS(gsrc + (size_t)64 * 1024, ldst + 64 * 64);
    };

    int aoff[2], boff[2];
#pragma unroll
    for (int kh = 0; kh < 2; kh++) {
        const int sw = (((kh * 4 + quad) ^ (lo & 7)) * 8);
        aoff[kh] = (((wr & 1) * 64 + lo) * 64) + sw;
        boff[kh] = ((wc * 64 + lo) * 64) + sw;
    }
    const int slA = wr >> 1;  // which A half this wave reads

    // prologue: halves 0..4 in flight; complete 0..3 (tile 0), allow half 4.
#pragma unroll
    for (int h = 0; h < 5; h++) stage_half(h);
    asm volatile("s_waitcnt vmcnt(2)" ::: "memory");
    __builtin_amdgcn_s_barrier();

    for (int t = 0; t < 16; t++) {
        const int p4 = (t & 1) * 4;
        const short* LA  = &Lds[(p4 + slA) * 8192];
        const short* LB1 = &Lds[(p4 + 2) * 8192];
        const short* LB2 = &Lds[(p4 + 3) * 8192];
        const int hb = 4 * t;
        s8v af[4], bf[4];

        // ---- P1: B-quad 0, K-half 0
#pragma unroll
        for (int i = 0; i < 4; i++) af[i] = *(const s8v*)&LA[aoff[0] + i * 1024];
#pragma unroll
        for (int j = 0; j < 4; j++) bf[j] = *(const s8v*)&LB1[boff[0] + j * 1024];
        stage_half(hb + 5);
        __builtin_amdgcn_s_barrier();
        __builtin_amdgcn_s_setprio(1);
#pragma unroll
        for (int i = 0; i < 4; i++)
#pragma unroll
            for (int j = 0; j < 4; j++)
                accA[i][j] = __builtin_amdgcn_mfma_f32_16x16x32_bf16(af[i], bf[j], accA[i][j], 0, 0, 0);
        __builtin_amdgcn_s_setprio(0);
        __builtin_amdgcn_s_barrier();

        // ---- P2: B-quad 1, K-half 0 (reuse af)
#pragma unroll
        for (int j = 0; j < 4; j++) bf[j] = *(const s8v*)&LB2[boff[0] + j * 1024];
        stage_half(hb + 6);
        __builtin_amdgcn_s_barrier();
        __builtin_amdgcn_s_setprio(1);
#pragma unroll
        for (int i = 0; i < 4; i++)
#pragma unroll
            for (int j = 0; j < 4; j++)
                accB[i][j] = __builtin_amdgcn_mfma_f32_16x16x32_bf16(af[i], bf[j], accB[i][j], 0, 0, 0);
        __builtin_amdgcn_s_setprio(0);
        __builtin_amdgcn_s_barrier();

        // ---- P3: B-quad 0, K-half 1
#pragma unroll
        for (int i = 0; i < 4; i++) af[i] = *(const s8v*)&LA[aoff[1] + i * 1024];
#pragma unroll
        for (int j = 0; j < 4; j++) bf[j] = *(const s8v*)&LB1[boff[1] + j * 1024];
        stage_half(hb + 7);
        __builtin_amdgcn_s_barrier();
        __builtin_amdgcn_s_setprio(1);
#pragma unroll
        for (int i = 0; i < 4; i++)
#pragma unroll
            for (int j = 0; j < 4; j++)
                accA[i][j] = __builtin_amdgcn_mfma_f32_16x16x32_bf16(af[i], bf[j], accA[i][j], 0, 0, 0);
        __builtin_amdgcn_s_setprio(0);
        __builtin_amdgcn_s_barrier();

        // ---- P4: B-quad 1, K-half 1
#pragma unroll
        for (int j = 0; j < 4; j++) bf[j] = *(const s8v*)&LB2[boff[1] + j * 1024];
        stage_half(hb + 8);
        __builtin_amdgcn_s_barrier();
        __builtin_amdgcn_s_setprio(1);
#pragma unroll
        for (int i = 0; i < 4; i++)
#pragma unroll
            for (int j = 0; j < 4; j++)
                accB[i][j] = __builtin_amdgcn_mfma_f32_16x16x32_bf16(af[i], bf[j], accB[i][j], 0, 0, 0);
        __builtin_amdgcn_s_setprio(0);
        // tile boundary: counted wait BEFORE the barrier (publishes writes)
        if (t < 14)       { asm volatile("s_waitcnt vmcnt(2)" ::: "memory"); }
        else if (t == 14) { asm volatile("s_waitcnt vmcnt(0)" ::: "memory"); }
        __builtin_amdgcn_s_barrier();
    }

    // epilogue: per-1024-seg bias; sigmoid on G segment; dual quadrant write
    const int seg = n0 >> 10;
    const float* bp = (seg == 0) ? bias1 : (seg == 1) ? bias2 : (seg == 2) ? bias3 : bias4;
    const bool do_sig = (n0 >= 3072);
#pragma unroll
    for (int i = 0; i < 4; i++) {
#pragma unroll
        for (int j = 0; j < 4; j++) {
#pragma unroll
            for (int r = 0; r < 4; r++) {
                int gm = m0 + wr * 64 + i * 16 + quad * 4 + r;
                int gn = n0 + wc * 64 + j * 16 + lo;
                float a = accA[i][j][r] + bp[gn & 1023];
                float g = accB[i][j][r] + bp[(gn + 128) & 1023];
                if (do_sig) { a = sigf(a); g = sigf(g); }
                C[(size_t)gm * 4096 + gn]       = f2b(a);
                C[(size_t)gm * 4096 + gn + 128] = f2b(g);
            }
        }
    }
}

// ---------------------------------------------------------------------------
// Split-K single-B 8-phase-style GEMM for Wf2 (N=1024, K=4096). Verified R7.
// Tile 256x128, grid (8,16,2). 3 halves/tile, slot=h%6, 96 KB LDS.
// Ledger: end of tile t issued <=3t+6; vmcnt(2) completes <=3t+5 = tile t+1
// reads. stage(3t+6) overwrites own slot0 after P2's 2nd barrier (safe).
__global__ __launch_bounds__(512, 1) void gemm_sk8(
    const unsigned short* __restrict__ A,   // [4096][4096] bf16 (H1)
    const unsigned short* __restrict__ BT,  // [1024][4096] bf16 (Wf2T)
    float* __restrict__ P0, float* __restrict__ P1)
{
    constexpr int NT = 32;
    __shared__ short Lds[6 * 8192];  // 96 KB

    const int tid  = threadIdx.x;
    const int ln   = tid & 63, wv = tid >> 6;
    const int wr   = wv >> 1, wc = wv & 1;
    const int quad = ln >> 4, lo = ln & 15;
    const int m0   = blockIdx.y * 256, n0 = blockIdx.x * 128;
    const int kb   = blockIdx.z * 2048;
    float* const P = blockIdx.z ? P1 : P0;

    const int rowst = wv * 8 + (ln >> 3);
    const int cosrc = ((ln & 7) ^ (ln >> 3)) * 8;
    short* const ldst0 = &Lds[(wv * 8) * 64];

    f4 acc[4][4];
#pragma unroll
    for (int i = 0; i < 4; i++)
#pragma unroll
        for (int j = 0; j < 4; j++)
#pragma unroll
            for (int r = 0; r < 4; r++) acc[i][j][r] = 0.f;

    auto stage_half = [&](int h) {
        if (h >= 3 * NT) return;
        const int tt = h / 3, kind = h % 3, slot = h % 6;
        const unsigned short* gsrc;
        if (kind == 0)      gsrc = A  + (size_t)(m0 + rowst) * 4096 + kb + tt * 64 + cosrc;
        else if (kind == 1) gsrc = A  + (size_t)(m0 + 128 + rowst) * 4096 + kb + tt * 64 + cosrc;
        else                gsrc = BT + (size_t)(n0 + rowst) * 4096 + kb + tt * 64 + cosrc;
        short* ldst = ldst0 + slot * 8192;
        GL2LDS(gsrc,                     ldst);
        GL2LDS(gsrc + (size_t)64 * 4096, ldst + 64 * 64);
    };

    int aoff[2], boff[2];
#pragma unroll
    for (int kh = 0; kh < 2; kh++) {
        const int sw = (((kh * 4 + quad) ^ (lo & 7)) * 8);
        aoff[kh] = (((wr & 1) * 64 + lo) * 64) + sw;
        boff[kh] = ((wc * 64 + lo) * 64) + sw;
    }
    const int slA = wr >> 1;  // kind 0/1

#pragma unroll
    for (int h = 0; h < 4; h++) stage_half(h);
    asm volatile("s_waitcnt vmcnt(2)" ::: "memory");
    __builtin_amdgcn_s_barrier();

    for (int t = 0; t < NT; t++) {
        const int base = (t & 1) * 3;
        const short* LA = &Lds[(base + slA) * 8192];
        const short* LB = &Lds[(base + 2) * 8192];
        s8v af[4], bf[4];

        // ---- P1: K-half 0
#pragma unroll
        for (int i = 0; i < 4; i++) af[i] = *(const s8v*)&LA[aoff[0] + i * 1024];
#pragma unroll
        for (int j = 0; j < 4; j++) bf[j] = *(const s8v*)&LB[boff[0] + j * 1024];
        stage_half(3 * t + 4);
        __builtin_amdgcn_s_barrier();
        __builtin_amdgcn_s_setprio(1);
#pragma unroll
        for (int i = 0; i < 4; i++)
#pragma unroll
            for (int j = 0; j < 4; j++)
                acc[i][j] = __builtin_amdgcn_mfma_f32_16x16x32_bf16(af[i], bf[j], acc[i][j], 0, 0, 0);
        __builtin_amdgcn_s_setprio(0);
        __builtin_amdgcn_s_barrier();

        // ---- P2: K-half 1
#pragma unroll
        for (int i = 0; i < 4; i++) af[i] = *(const s8v*)&LA[aoff[1] + i * 1024];
#pragma unroll
        for (int j = 0; j < 4; j++) bf[j] = *(const s8v*)&LB[boff[1] + j * 1024];
        stage_half(3 * t + 5);
        __builtin_amdgcn_s_barrier();
        __builtin_amdgcn_s_setprio(1);
#pragma unroll
        for (int i = 0; i < 4; i++)
#pragma unroll
            for (int j = 0; j < 4; j++)
                acc[i][j] = __builtin_amdgcn_mfma_f32_16x16x32_bf16(af[i], bf[j], acc[i][j], 0, 0, 0);
        __builtin_amdgcn_s_setprio(0);
        __builtin_amdgcn_s_barrier();

        // ---- tile end
        stage_half(3 * t + 6);
        if (t < NT - 2)       { asm volatile("s_waitcnt vmcnt(2)" ::: "memory"); }
        else if (t == NT - 2) { asm volatile("s_waitcnt vmcnt(0)" ::: "memory"); }
        __builtin_amdgcn_s_barrier();
    }

#pragma unroll
    for (int i = 0; i < 4; i++) {
#pragma unroll
        for (int j = 0; j < 4; j++) {
#pragma unroll
            for (int r = 0; r < 4; r++) {
                int gm = m0 + wr * 64 + i * 16 + quad * 4 + r;
                int gn = n0 + wc * 64 + j * 16 + lo;
                P[(size_t)gm * 1024 + gn] = acc[i][j][r];
            }
        }
    }
}

// ---------------------------------------------------------------------------
// Flash attention, fixed-shift softmax. R2-verified config: 16 q/wave,
// KVBLK=32, grid 16x64 = 1024 blocks = 4/CU.
__global__ __launch_bounds__(256) void attn_kernel(
    const unsigned short* __restrict__ QKVG, const float* __restrict__ bias,
    unsigned short* __restrict__ ctx)
{
    __shared__ short Ks[32 * 72];     // [kv][d]
    __shared__ short Vt[64 * 48];     // [d][perm kv]
    __shared__ short Ps[4][16 * 40];  // per-wave P [q][perm kv]

    const int tid = threadIdx.x;
    const int lane = tid & 63, wave = tid >> 6;
    const int quad = lane >> 4, lo = lane & 15;
    const int bh = blockIdx.y;
    const int b = bh >> 4, h = bh & 15;
    const int q0 = blockIdx.x * 64 + wave * 16;
    const size_t base  = (size_t)b * NS * 4096 + (size_t)h * 64;
    const size_t baseK = base + 1024, baseV = base + 2048;
    constexpr float c1 = 0.125f * 1.44269504f;

    s8v aq0 = *(const s8v*)(QKVG + base + (size_t)(q0 + lo) * 4096 + quad * 8);
    s8v aq1 = *(const s8v*)(QKVG + base + (size_t)(q0 + lo) * 4096 + 32 + quad * 8);

    f4 accO[4];
    float l_r[4];
#pragma unroll
    for (int r = 0; r < 4; r++) {
        l_r[r] = 0.f;
#pragma unroll
        for (int j = 0; j < 4; j++) accO[j][r] = 0.f;
    }

    const int skv = tid >> 3, sd8 = (tid & 7) * 8;
    const int vkv = tid & 31, vd8 = (tid >> 5) * 8;
    const int pvk = 2 * (vkv & 15) + (vkv >> 4);

    s8v kk = *(const s8v*)(QKVG + baseK + (size_t)skv * 4096 + sd8);
    s8v vv = *(const s8v*)(QKVG + baseV + (size_t)vkv * 4096 + vd8);

    for (int kv0 = 0; kv0 < NS; kv0 += 32) {
        *(s8v*)&Ks[skv * 72 + sd8] = kk;
#pragma unroll
        for (int i = 0; i < 8; i++) Vt[(vd8 + i) * 48 + pvk] = (short)vv[i];
        __syncthreads();

        s8v kkn = kk, vvn = vv;
        if (kv0 + 32 < NS) {
            kkn = *(const s8v*)(QKVG + baseK + (size_t)(kv0 + 32 + skv) * 4096 + sd8);
            vvn = *(const s8v*)(QKVG + baseV + (size_t)(kv0 + 32 + vkv) * 4096 + vd8);
        }

        f4 sc[2];
#pragma unroll
        for (int cb = 0; cb < 2; cb++) {
            s8v bk0 = *(const s8v*)&Ks[(cb * 16 + lo) * 72 + quad * 8];
            s8v bk1 = *(const s8v*)&Ks[(cb * 16 + lo) * 72 + 32 + quad * 8];
            f4 z;
#pragma unroll
            for (int r = 0; r < 4; r++) z[r] = 0.f;
            z = __builtin_amdgcn_mfma_f32_16x16x32_bf16(aq0, bk0, z, 0, 0, 0);
            sc[cb] = __builtin_amdgcn_mfma_f32_16x16x32_bf16(aq1, bk1, z, 0, 0, 0);
        }

        int* PsI = (int*)&Ps[wave][0];
#pragma unroll
        for (int r = 0; r < 4; r++) {
            int qrow = q0 + quad * 4 + r;
            const float* bp = &bias[(size_t)qrow * NS + kv0];
            float p0 = exp2f(sc[0][r] * c1 + bp[lo]);
            float p1 = exp2f(sc[1][r] * c1 + bp[16 + lo]);
            l_r[r] += p0 + p1;
            unsigned int pk = (unsigned int)f2b(p0) | ((unsigned int)f2b(p1) << 16);
            PsI[(quad * 4 + r) * 20 + lo] = (int)pk;
        }
        s8v pf = *(const s8v*)&Ps[wave][lo * 40 + quad * 8];
#pragma unroll
        for (int j = 0; j < 4; j++) {
            s8v bv = *(const s8v*)&Vt[(j * 16 + lo) * 48 + quad * 8];
            accO[j] = __builtin_amdgcn_mfma_f32_16x16x32_bf16(pf, bv, accO[j], 0, 0, 0);
        }
        __syncthreads();
        kk = kkn; vv = vvn;
    }

#pragma unroll
    for (int r = 0; r < 4; r++) {
        float l = l_r[r];
#pragma unroll
        for (int d = 1; d < 16; d <<= 1) l += __shfl_xor(l, d, 64);
        l_r[r] = 1.f / l;
    }
#pragma unroll
    for (int j = 0; j < 4; j++)
#pragma unroll
        for (int r = 0; r < 4; r++) {
            int qrow = q0 + quad * 4 + r;
            ctx[((size_t)b * NS + qrow) * 1024 + h * 64 + j * 16 + lo] = f2b(accO[j][r] * l_r[r]);
        }
}

// ---------------------------------------------------------------------------
// LayerNorm over last dim (1024). X bf16 in, bf16 out (ln1 path).
__global__ __launch_bounds__(256) void ln_kernel(
    const unsigned short* __restrict__ X, const float* __restrict__ g,
    const float* __restrict__ bb, unsigned short* __restrict__ out)
{
    const int row = blockIdx.x;
    const unsigned short* xr = X + (size_t)row * NE;
    s4v xv = *(const s4v*)(xr + threadIdx.x * 4);
    float v[4], s = 0.f, ss = 0.f;
#pragma unroll
    for (int i = 0; i < 4; i++) {
        v[i] = b2f((unsigned short)xv[i]);
        s += v[i]; ss += v[i] * v[i];
    }
#pragma unroll
    for (int d = 1; d < 64; d <<= 1) { s += __shfl_xor(s, d, 64); ss += __shfl_xor(ss, d, 64); }
    __shared__ float red[8];
    int wave = threadIdx.x >> 6, lane = threadIdx.x & 63;
    if (lane == 0) { red[wave] = s; red[4 + wave] = ss; }
    __syncthreads();
    s  = red[0] + red[1] + red[2] + red[3];
    ss = red[4] + red[5] + red[6] + red[7];
    float mu = s * (1.f / NE);
    float var = ss * (1.f / NE) - mu * mu;
    float rstd = rsqrtf(fmaxf(var, 0.f) + 1e-6f);
#pragma unroll
    for (int i = 0; i < 4; i++) {
        int c = threadIdx.x * 4 + i;
        float o = (v[i] - mu) * rstd * g[c] + bb[c];
        out[(size_t)row * NE + c] = f2b(o);
    }
}

// ---------------------------------------------------------------------------
// Fused split-K reduce + residual + bias + LayerNorm (ln2 path):
// t = X1 + P0 + P1 + bf2;  out = LN(t) (f32).
__global__ __launch_bounds__(256) void ln2red_kernel(
    const unsigned short* __restrict__ X1,
    const float* __restrict__ P0, const float* __restrict__ P1,
    const float* __restrict__ bf2,
    const float* __restrict__ g, const float* __restrict__ bb,
    float* __restrict__ out)
{
    const int row = blockIdx.x;
    const size_t rb = (size_t)row * NE;
    s4v xv = *(const s4v*)(X1 + rb + threadIdx.x * 4);
    f4 p0 = *(const f4*)(P0 + rb + threadIdx.x * 4);
    f4 p1 = *(const f4*)(P1 + rb + threadIdx.x * 4);
    float v[4], s = 0.f, ss = 0.f;
#pragma unroll
    for (int i = 0; i < 4; i++) {
        int c = threadIdx.x * 4 + i;
        v[i] = b2f((unsigned short)xv[i]) + p0[i] + p1[i] + bf2[c];
        s += v[i]; ss += v[i] * v[i];
    }
#pragma unroll
    for (int d = 1; d < 64; d <<= 1) { s += __shfl_xor(s, d, 64); ss += __shfl_xor(ss, d, 64); }
    __shared__ float red[8];
    int wave = threadIdx.x >> 6, lane = threadIdx.x & 63;
    if (lane == 0) { red[wave] = s; red[4 + wave] = ss; }
    __syncthreads();
    s  = red[0] + red[1] + red[2] + red[3];
    ss = red[4] + red[5] + red[6] + red[7];
    float mu = s * (1.f / NE);
    float var = ss * (1.f / NE) - mu * mu;
    float rstd = rsqrtf(fmaxf(var, 0.f) + 1e-6f);
#pragma unroll
    for (int i = 0; i < 4; i++) {
        int c = threadIdx.x * 4 + i;
        out[rb + c] = (v[i] - mu) * rstd * g[c] + bb[c];
    }
}

// ---------------------------------------------------------------------------
// Workspace map (peak 78 MB):
//   [0,8)   xb -> T1
//   [8,16)  WTqkvg -> Cx -> X1
//   [16,18) WoT   [18,26) Wf1T   [26,34) WfgT   [34,42) Wf2T
//   [42,46) biasP (fp32, log2-domain, shift folded)
//   [46,78) QKVG -> H1
//   Wf2 split-K partials: P0 -> [18,34) (Wf1T/WfgT, dead after FF GEMM);
//   P1 -> d_out (f32 16MB, overwritten by ln2red afterwards).
extern "C" void kernel_launch(void* const* d_in, const int* in_sizes, int n_in,
                              void* d_out, int out_size, void* d_ws, size_t ws_size,
                              hipStream_t stream)
{
    const float* x    = (const float*)d_in[0];
    const float* pe   = (const float*)d_in[1];
    const float* Wq   = (const float*)d_in[2];
    const float* bq   = (const float*)d_in[3];
    const float* Wk   = (const float*)d_in[4];
    const float* bk   = (const float*)d_in[5];
    const float* Wv   = (const float*)d_in[6];
    const float* bv   = (const float*)d_in[7];
    const float* Wo   = (const float*)d_in[8];
    const float* bo   = (const float*)d_in[9];
    const float* Wg   = (const float*)d_in[10];
    const float* bg   = (const float*)d_in[11];
    const float* Wf1  = (const float*)d_in[12];
    const float* bf1  = (const float*)d_in[13];
    const float* Wfg  = (const float*)d_in[14];
    const float* bfg  = (const float*)d_in[15];
    const float* Wf2  = (const float*)d_in[16];
    const float* bf2  = (const float*)d_in[17];
    const float* ln1g = (const float*)d_in[18];
    const float* ln1b = (const float*)d_in[19];
    const float* ln2g = (const float*)d_in[20];
    const float* ln2b = (const float*)d_in[21];

    char* ws = (char*)d_ws;
    unsigned short* xb    = (unsigned short*)ws;                         // [0,8)
    unsigned short* WTq   = (unsigned short*)(ws + ( 8ull << 20));       // [8,16)
    unsigned short* WoT   = (unsigned short*)(ws + (16ull << 20));       // [16,18)
    unsigned short* Wf1T  = (unsigned short*)(ws + (18ull << 20));       // [18,26)
    unsigned short* WfgT  = (unsigned short*)(ws + (26ull << 20));       // [26,34)
    unsigned short* Wf2T  = (unsigned short*)(ws + (34ull << 20));       // [34,42)
    float*          biasP = (float*)(ws + (42ull << 20));                // [42,46)
    unsigned short* QKVG  = (unsigned short*)(ws + (46ull << 20));       // [46,78)
    unsigned short* T1 = xb;
    unsigned short* Cx = WTq;
    unsigned short* X1 = WTq;
    unsigned short* H1 = QKVG;
    float* P0 = (float*)(ws + (18ull << 20));   // aliases Wf1T/WfgT (dead)
    float* P1 = (float*)d_out;                  // overwritten by ln2red

    dim3 blk(256);

    // fused prep: cvt_x | 5x ExE WT | Wf1T/WfgT | Wf2T | posmean
    prep_kernel<<<dim3(2048 + 1280 + 2048 + 1024 + 4096), blk, 0, stream>>>(
        x, xb, Wq, Wk, Wv, Wg, Wo, WTq, WoT,
        Wf1, Wfg, Wf2, Wf1T, WfgT, Wf2T, pe, biasP);

    // fused QKVG: verbatim-ff8-clone dual-quadrant kernel, 256x256, grid 16x16
    gemm_qkvgf<<<dim3(16, 16), dim3(512), 0, stream>>>(
        xb, WTq, WTq + 128 * 1024, bq, bk, bv, bg, QKVG);

    attn_kernel<<<dim3(NS / 64, NB * NH), blk, 0, stream>>>(QKVG, biasP, Cx);

    // T1 = xb + G * (Cx@Wo + bo)   (T1 aliases xb: same-idx read-then-write)
    gemm_gate<2><<<dim3(8, 64), blk, 0, stream>>>(
        Cx, WoT, bo, xb, QKVG + 3072, T1, NM, NE, NE);
    ln_kernel<<<dim3(NM), blk, 0, stream>>>(T1, ln1g, ln1b, X1);

    // fused FF: dedicated 8-phase kernel (R6-verified source)
    gemm_ff8<<<dim3(NFF / 128, NM / 256), dim3(512), 0, stream>>>(
        X1, Wf1T, WfgT, bf1, bfg, H1);

    // Wf2: split-K=2 8-phase-style, f32 partials
    gemm_sk8<<<dim3(8, 16, 2), dim3(512), 0, stream>>>(H1, Wf2T, P0, P1);

    // fused reduce + residual + bias + LN2 -> d_out (f32)
    ln2red_kernel<<<dim3(NM), blk, 0, stream>>>(
        X1, P0, P1, bf2, ln2g, ln2b, (float*)d_out);
}